// Round 12
// baseline (254.935 us; speedup 1.0000x reference)
//
#include <hip/hip_runtime.h>
#include <stdint.h>
#include <stddef.h>

#define DEVINL __device__ __forceinline__

typedef unsigned short u16;
typedef unsigned int u32;
typedef __attribute__((ext_vector_type(8))) short short8;
typedef __attribute__((ext_vector_type(4))) float f32x4;
typedef __attribute__((ext_vector_type(4))) u32 u32x4;
typedef __attribute__((ext_vector_type(2))) u32 u32x2;

// log2(e)/8 : folded into W_q / b_q so flash's exp2 needs no multiply
#define QSCALE 0.18033688011112042f

// ---------- helpers ----------
DEVINL u16 f2bf(float f) {
    u32 u = __builtin_bit_cast(u32, f);
    u32 r = (u + 0x7fffu + ((u >> 16) & 1u)) >> 16;   // RNE
    return (u16)r;
}

DEVINL void gld_lds16(const void* g, void* l) {
    __builtin_amdgcn_global_load_lds(
        (__attribute__((address_space(1))) u32*)(uintptr_t)g,
        (__attribute__((address_space(3))) u32*)l, 16, 0, 0);
}

// pack two fp32 -> bf16x2 by truncation (bias cancels: denominator sums the same bf16 P)
DEVINL u32 pack_bf16_trunc(float lo, float hi) {
    return __builtin_amdgcn_perm(__builtin_bit_cast(u32, hi),
                                 __builtin_bit_cast(u32, lo), 0x07060302u);
}

// cross-lane half swaps (gfx950): both outputs are used.
DEVINL void plswap32(u32 &a, u32 &b) {
#if __has_builtin(__builtin_amdgcn_permlane32_swap)
    u32x2 r = __builtin_amdgcn_permlane32_swap(a, b, false, false);
    a = r[0]; b = r[1];
#else
    asm("v_permlane32_swap_b32 %0, %1" : "+v"(a), "+v"(b));
#endif
}
DEVINL void plswap16(u32 &a, u32 &b) {
#if __has_builtin(__builtin_amdgcn_permlane16_swap)
    u32x2 r = __builtin_amdgcn_permlane16_swap(a, b, false, false);
    a = r[0]; b = r[1];
#else
    asm("v_permlane16_swap_b32 %0, %1" : "+v"(a), "+v"(b));
#endif
}

// ---------- fused input prep: casts + scale folding, one launch ----------
// blocks [0,4096): x -> xb ; [4096,5632): w_qkv -> wqb (Q rows scaled)
// [5632,6144): w_o -> wob ; [6144,6156): b_qkv scale -> bsc
__global__ void prep_inputs(const float* __restrict__ x, const float* __restrict__ wqkv,
                            const float* __restrict__ bqkv, const float* __restrict__ wo,
                            u16* __restrict__ xb, u16* __restrict__ wqb,
                            u16* __restrict__ wob, float* __restrict__ bsc) {
    int blk = blockIdx.x;
    if (blk < 6144) {
        const float* src; u16* dst; int base; bool qscale = false;
        if (blk < 4096)      { src = x;    dst = xb;  base = blk; }
        else if (blk < 5632) { src = wqkv; dst = wqb; base = blk - 4096; qscale = true; }
        else                 { src = wo;   dst = wob; base = blk - 5632; }
        int i = (base * 256 + threadIdx.x) * 8;
        float sc = 1.0f;
        if (qscale) { int row = i >> 10; if ((row % 192) < 64) sc = QSCALE; }
        float4 a = *(const float4*)(src + i);
        float4 c = *(const float4*)(src + i + 4);
        union { u16 s[8]; u32x4 v; } t;
        t.s[0] = f2bf(a.x * sc); t.s[1] = f2bf(a.y * sc); t.s[2] = f2bf(a.z * sc); t.s[3] = f2bf(a.w * sc);
        t.s[4] = f2bf(c.x * sc); t.s[5] = f2bf(c.y * sc); t.s[6] = f2bf(c.z * sc); t.s[7] = f2bf(c.w * sc);
        *(u32x4*)(dst + i) = t.v;
    } else {
        int i = (blk - 6144) * 256 + threadIdx.x;   // 0..3071
        float sc = ((i % 192) < 64) ? QSCALE : 1.0f;
        bsc[i] = bqkv[i] * sc;
    }
}

// ---------- QKV GEMM  qkv[M,3072] = x[M,K] * w_qkv[3072,K]^T + b ----------
// Round-12: flash-style DOUBLE-BUFFERED staging (prefetch next BK=64 tile
// before computing current; single barrier per K-step — exact loop structure
// verified in flash_attn since R3).  LDS 64 KB (2 buffers), same verified
// zero-conflict geometry: linear dest + pre-swizzled source granule
// lgr=(lane&7)^(row&7); fragment reads XOR (l15&7)*8.  Diagnosis: 76 us with
// MfmaUtil 28 / VALU 20 / HBM 14% and minimal FETCH -> latency-bound on the
// serial stage->vmcnt(0)drain->compute chain; dbuf hides stage latency under
// the previous tile's compute.  XCD-aware 1-D grid remap unchanged.
__global__ void gemm_qkv(const u16* __restrict__ A, const u16* __restrict__ Bm,
                         const float* __restrict__ bias, u16* __restrict__ qkvb,
                         u16* __restrict__ vtb) {
    const int K = 1024, N = 3072;
    __shared__ u16 As[2][128 * 64];   // 2 x 16 KB
    __shared__ u16 Bs[2][128 * 64];   // 2 x 16 KB
    const int tid = threadIdx.x;
    const int lane = tid & 63;
    const int wv = tid >> 6, wr = wv >> 1, wc = wv & 1;
    const int l15 = lane & 15, quad = lane >> 4;
    const int e7 = (l15 & 7) * 8;              // u16-unit XOR for swizzled reads
    const int id = blockIdx.x;                 // 0..1535
    const int xcd = id & 7, rr = id >> 3;      // rr: 0..191
    const int m0 = ((xcd << 3) + rr / 24) * 128;
    const int n0 = (rr % 24) * 128;

    f32x4 acc[4][4];
#pragma unroll
    for (int i = 0; i < 4; i++)
#pragma unroll
        for (int j = 0; j < 4; j++) acc[i][j] = (f32x4){0.f, 0.f, 0.f, 0.f};

    const u16* Ab = A + (size_t)m0 * K;
    const u16* Bb = Bm + (size_t)n0 * K;
    const int lrow = lane >> 3;
    const int lgr  = (lane & 7) ^ lrow;
    const int r0   = wv * 8 + lrow;

    // prologue: stage k0=0 into buffer 0
#pragma unroll
    for (int j = 0; j < 4; j++) {
        int row = j * 32 + r0;
        gld_lds16(Ab + (size_t)row * K + lgr * 8, (char*)&As[0][0] + (size_t)(j * 256 + tid) * 16);
        gld_lds16(Bb + (size_t)row * K + lgr * 8, (char*)&Bs[0][0] + (size_t)(j * 256 + tid) * 16);
    }
    __syncthreads();

    int cur = 0;
    for (int k0 = 0; k0 < K; k0 += 64) {
        // prefetch next tile into the other buffer (hidden under compute)
        if (k0 + 64 < K) {
            int nb = cur ^ 1;
#pragma unroll
            for (int j = 0; j < 4; j++) {
                int row = j * 32 + r0;
                gld_lds16(Ab + (size_t)row * K + k0 + 64 + lgr * 8,
                          (char*)&As[nb][0] + (size_t)(j * 256 + tid) * 16);
                gld_lds16(Bb + (size_t)row * K + k0 + 64 + lgr * 8,
                          (char*)&Bs[nb][0] + (size_t)(j * 256 + tid) * 16);
            }
        }
#pragma unroll
        for (int ks = 0; ks < 2; ks++) {
            short8 af[4], bf8[4];
#pragma unroll
            for (int mi = 0; mi < 4; mi++)
                af[mi] = *(const short8*)(&As[cur][0] + (wr * 64 + mi * 16 + l15) * 64 + ((ks * 32 + quad * 8) ^ e7));
#pragma unroll
            for (int ni = 0; ni < 4; ni++)
                bf8[ni] = *(const short8*)(&Bs[cur][0] + (wc * 64 + ni * 16 + l15) * 64 + ((ks * 32 + quad * 8) ^ e7));
#pragma unroll
            for (int mi = 0; mi < 4; mi++)
#pragma unroll
                for (int ni = 0; ni < 4; ni++)
                    acc[mi][ni] = __builtin_amdgcn_mfma_f32_16x16x32_bf16(af[mi], bf8[ni], acc[mi][ni], 0, 0, 0);
        }
        __syncthreads();   // implicit vmcnt(0): prefetch complete; reads of [cur] done
        cur ^= 1;
    }

#pragma unroll
    for (int mi = 0; mi < 4; mi++) {
        int row_b = m0 + wr * 64 + mi * 16 + quad * 4;
#pragma unroll
        for (int ni = 0; ni < 4; ni++) {
            int c0 = n0 + wc * 64 + ni * 16;          // group base (16-aligned)
            int sec0 = c0 % 192;                       // section offset, wave-uniform
            float bv = bias[c0 + l15];
            float v0 = acc[mi][ni][0] + bv;
            float v1 = acc[mi][ni][1] + bv;
            float v2 = acc[mi][ni][2] + bv;
            float v3 = acc[mi][ni][3] + bv;
            if (sec0 >= 128) {
                // V element: transpose-store to vt[bh][d][s], 4 consecutive s
                int hh = c0 / 192;
                int b = row_b >> 11;
                int s = row_b & 2047;
                int d = sec0 - 128 + l15;
                u32 lo = (u32)f2bf(v0) | ((u32)f2bf(v1) << 16);
                u32 hi = (u32)f2bf(v2) | ((u32)f2bf(v3) << 16);
                *(u32x2*)(vtb + ((size_t)((b * 16 + hh) * 64 + d)) * 2048 + s) = (u32x2){lo, hi};
            } else {
                int col = c0 + l15;
                qkvb[(size_t)(row_b + 0) * N + col] = f2bf(v0);
                qkvb[(size_t)(row_b + 1) * N + col] = f2bf(v1);
                qkvb[(size_t)(row_b + 2) * N + col] = f2bf(v2);
                qkvb[(size_t)(row_b + 3) * N + col] = f2bf(v3);
            }
        }
    }
}

// ---------- out GEMM  out[M,1024] = vals2[M,K] * w_o[1024,K]^T + b_o ----------
// ROUND-12: reverted to the R10-verified 128x64 / 1024-block form (4 blocks/CU;
// the R11 128x128@512-blocks version regressed ~7 us from 2-blocks/CU latency
// starvation).  BK=64 flash-pattern LDS (zero-conflict), XCD remap.
__global__ void gemm_out(const u16* __restrict__ A, const u16* __restrict__ Bm,
                         const float* __restrict__ bias, float* __restrict__ C) {
    const int K = 1024, N = 1024;
    __shared__ u16 As[128 * 64];   // 16 KB
    __shared__ u16 Bs[64 * 64];    // 8 KB
    const int tid = threadIdx.x;
    const int lane = tid & 63;
    const int wv = tid >> 6, wr = wv >> 1, wc = wv & 1;
    const int l15 = lane & 15, quad = lane >> 4;
    const int e7 = (l15 & 7) * 8;
    const int id = blockIdx.x;                 // 0..1023
    const int xcd = id & 7, rr = id >> 3;      // rr: 0..127
    const int m0 = ((xcd << 3) + (rr >> 4)) * 128;
    const int n0 = (rr & 15) * 64;

    f32x4 acc[4][2];
#pragma unroll
    for (int i = 0; i < 4; i++)
#pragma unroll
        for (int j = 0; j < 2; j++) acc[i][j] = (f32x4){0.f, 0.f, 0.f, 0.f};

    const u16* Ab = A + (size_t)m0 * K;
    const u16* Bb = Bm + (size_t)n0 * K;
    const int lrow = lane >> 3;
    const int lgr  = (lane & 7) ^ lrow;
    const int r0   = wv * 8 + lrow;

    for (int k0 = 0; k0 < K; k0 += 64) {
#pragma unroll
        for (int j = 0; j < 4; j++)
            gld_lds16(Ab + (size_t)(j * 32 + r0) * K + k0 + lgr * 8,
                      (char*)As + (size_t)(j * 256 + tid) * 16);
#pragma unroll
        for (int j = 0; j < 2; j++)
            gld_lds16(Bb + (size_t)(j * 32 + r0) * K + k0 + lgr * 8,
                      (char*)Bs + (size_t)(j * 256 + tid) * 16);
        __syncthreads();
#pragma unroll
        for (int ks = 0; ks < 2; ks++) {
            short8 af[4], bf8[2];
#pragma unroll
            for (int mi = 0; mi < 4; mi++)
                af[mi] = *(const short8*)(As + (wr * 64 + mi * 16 + l15) * 64 + ((ks * 32 + quad * 8) ^ e7));
#pragma unroll
            for (int ni = 0; ni < 2; ni++)
                bf8[ni] = *(const short8*)(Bs + (wc * 32 + ni * 16 + l15) * 64 + ((ks * 32 + quad * 8) ^ e7));
#pragma unroll
            for (int mi = 0; mi < 4; mi++)
#pragma unroll
                for (int ni = 0; ni < 2; ni++)
                    acc[mi][ni] = __builtin_amdgcn_mfma_f32_16x16x32_bf16(af[mi], bf8[ni], acc[mi][ni], 0, 0, 0);
        }
        __syncthreads();
    }

#pragma unroll
    for (int mi = 0; mi < 4; mi++) {
        int row_b = m0 + wr * 64 + mi * 16 + quad * 4;
#pragma unroll
        for (int ni = 0; ni < 2; ni++) {
            int col = n0 + wc * 32 + ni * 16 + l15;
            float bv = bias[col];
#pragma unroll
            for (int r = 0; r < 4; r++)
                C[(size_t)(row_b + r) * N + col] = acc[mi][ni][r] + bv;
        }
    }
}

// ---------- flash attention (round-12 = round-11, measured <=76 us — unchanged) ----------
// 16x16 MFMA, in-register P via permlane swaps, ZERO-C init, 8-wave 256-q
// blocks, 128-key tiles staged as two verified 64x64 sub-tiles, double-buffer,
// one barrier per 128 keys, XCD-aware remap, setprio.
__launch_bounds__(512, 4)
__global__ void flash_attn(const u16* __restrict__ qkv, const u16* __restrict__ vt,
                           u16* __restrict__ vals2) {
    __shared__ u16 Ks[2][2][64 * 64];   // [dbuf][subtile]: 64 keys x 64 d (swizzled)
    __shared__ u16 Vts[2][2][64 * 64];  // [dbuf][subtile]: 64 d x 64 keys (swizzled)

    const int tid = threadIdx.x;
    const int lane = tid & 63, wv = tid >> 6;      // wv: 0..7
    const int l15 = lane & 15, quad = lane >> 4;
    const int e7 = (l15 & 7) * 8;          // u16-unit XOR for swizzled reads
    // XCD-aware decode of the 1-D block id (512 blocks: 8 bh x 8 s-tiles per XCD)
    const int id = blockIdx.x;
    const int m = id >> 3;                  // 0..63
    const int bh = ((id & 7) << 3) + (m >> 3);
    const int s0 = (m & 7) << 8;            // 256-q tiles
    const int b = bh >> 4, h = bh & 15;

    // Q fragments in registers (q rows pre-scaled by log2e/8 at cast time)
    short8 qf[2][2];
    const u16* qbase = qkv + (size_t)(b * 2048 + s0 + wv * 32) * 3072 + h * 192;
#pragma unroll
    for (int qi = 0; qi < 2; qi++)
#pragma unroll
        for (int ks = 0; ks < 2; ks++)
            qf[qi][ks] = *(const short8*)(qbase + (size_t)(qi * 16 + l15) * 3072 + ks * 32 + quad * 8);

    f32x4 o_acc[2][4];
    f32x4 sum_acc[2];
#pragma unroll
    for (int qi = 0; qi < 2; qi++) {
        sum_acc[qi] = (f32x4){0.f, 0.f, 0.f, 0.f};
#pragma unroll
        for (int nd = 0; nd < 4; nd++) o_acc[qi][nd] = (f32x4){0.f, 0.f, 0.f, 0.f};
    }
    const f32x4 fzero = (f32x4){0.f, 0.f, 0.f, 0.f};

    const u16* kg = qkv + (size_t)(b * 2048) * 3072 + h * 192 + 64;
    const u16* vg = vt + (size_t)bh * 64 * 2048;

    // staging geometry: thread covers row wv*8 + (lane>>3) (8 waves -> 64 rows);
    // physical granule lane&7 holds logical granule (lane&7)^(row&7).
    const int lrow = lane >> 3;
    const int lgr  = (lane & 7) ^ lrow;
    const int r0   = wv * 8 + lrow;

    const short8 ones = (short8){0x3F80, 0x3F80, 0x3F80, 0x3F80, 0x3F80, 0x3F80, 0x3F80, 0x3F80};

    // prologue: stage tile 0 (both sub-tiles) into buffer 0
#pragma unroll
    for (int st = 0; st < 2; st++) {
        gld_lds16(kg + (size_t)(st * 64 + r0) * 3072 + lgr * 8,
                  (char*)&Ks[0][st][0] + (size_t)tid * 16);
        gld_lds16(vg + (size_t)r0 * 2048 + st * 64 + lgr * 8,
                  (char*)&Vts[0][st][0] + (size_t)tid * 16);
    }
    __syncthreads();

    int cur = 0;
    for (int kb = 0; kb < 2048; kb += 128) {
        // prefetch next 128-key tile into the other buffer (hidden under compute)
        if (kb + 128 < 2048) {
            int nb = cur ^ 1;
#pragma unroll
            for (int st = 0; st < 2; st++) {
                gld_lds16(kg + (size_t)(kb + 128 + st * 64 + r0) * 3072 + lgr * 8,
                          (char*)&Ks[nb][st][0] + (size_t)tid * 16);
                gld_lds16(vg + (size_t)r0 * 2048 + kb + 128 + st * 64 + lgr * 8,
                          (char*)&Vts[nb][st][0] + (size_t)tid * 16);
            }
        }

#pragma unroll
        for (int st = 0; st < 2; st++) {
            const u16* Kc = &Ks[cur][st][0];
            const u16* Vc = &Vts[cur][st][0];

            // S^T = K * Q^T : s_acc[ki][qi] -> key = ki*16+quad*4+r, q = qi*16+l15
            // first k-slice uses C=fzero (no per-tile accumulator zero-init movs)
            f32x4 s_acc[4][2];
            __builtin_amdgcn_s_setprio(1);
#pragma unroll
            for (int ki = 0; ki < 4; ki++) {
                short8 kf0 = *(const short8*)(Kc + (ki * 16 + l15) * 64 + ((quad * 8) ^ e7));
                short8 kf1 = *(const short8*)(Kc + (ki * 16 + l15) * 64 + ((32 + quad * 8) ^ e7));
#pragma unroll
                for (int qi = 0; qi < 2; qi++)
                    s_acc[ki][qi] = __builtin_amdgcn_mfma_f32_16x16x32_bf16(kf0, qf[qi][0], fzero, 0, 0, 0);
#pragma unroll
                for (int qi = 0; qi < 2; qi++)
                    s_acc[ki][qi] = __builtin_amdgcn_mfma_f32_16x16x32_bf16(kf1, qf[qi][1], s_acc[ki][qi], 0, 0, 0);
            }
            __builtin_amdgcn_s_setprio(0);

            // P = exp2(S^T) -> pack bf16 pairs -> permlane swaps build PV A-frags
            short8 ap[2][2];   // [qi][c]: P[q=l15][key=c*32+quad*8+0..7]
#pragma unroll
            for (int c = 0; c < 2; c++)
#pragma unroll
                for (int qi = 0; qi < 2; qi++) {
                    u32 w0 = pack_bf16_trunc(__builtin_amdgcn_exp2f(s_acc[2 * c][qi][0]),
                                             __builtin_amdgcn_exp2f(s_acc[2 * c][qi][1]));
                    u32 w1 = pack_bf16_trunc(__builtin_amdgcn_exp2f(s_acc[2 * c][qi][2]),
                                             __builtin_amdgcn_exp2f(s_acc[2 * c][qi][3]));
                    u32 w2 = pack_bf16_trunc(__builtin_amdgcn_exp2f(s_acc[2 * c + 1][qi][0]),
                                             __builtin_amdgcn_exp2f(s_acc[2 * c + 1][qi][1]));
                    u32 w3 = pack_bf16_trunc(__builtin_amdgcn_exp2f(s_acc[2 * c + 1][qi][2]),
                                             __builtin_amdgcn_exp2f(s_acc[2 * c + 1][qi][3]));
                    plswap32(w0, w2);
                    plswap32(w1, w3);
                    plswap16(w0, w2);
                    plswap16(w1, w3);
                    u32x4 wf = (u32x4){w0, w1, w2, w3};
                    ap[qi][c] = __builtin_bit_cast(short8, wf);
                }

            // PV over 2 chunks of 32 keys; denominator via ones-column MFMA
#pragma unroll
            for (int c = 0; c < 2; c++) {
#pragma unroll
                for (int qi = 0; qi < 2; qi++)
                    sum_acc[qi] = __builtin_amdgcn_mfma_f32_16x16x32_bf16(ap[qi][c], ones, sum_acc[qi], 0, 0, 0);
                __builtin_amdgcn_s_setprio(1);
#pragma unroll
                for (int nd = 0; nd < 4; nd++) {
                    short8 bv = *(const short8*)(Vc + (nd * 16 + l15) * 64 + ((c * 32 + quad * 8) ^ e7));
#pragma unroll
                    for (int qi = 0; qi < 2; qi++)
                        o_acc[qi][nd] = __builtin_amdgcn_mfma_f32_16x16x32_bf16(ap[qi][c], bv, o_acc[qi][nd], 0, 0, 0);
                }
                __builtin_amdgcn_s_setprio(0);
            }
        }

        __syncthreads();   // implicit vmcnt(0): prefetch complete; all reads of [cur] done
        cur ^= 1;
    }

    // epilogue: normalize (sum is broadcast across l15 by the ones-MFMA) and
    // write vals2 in the no-head-transpose reshape layout.
#pragma unroll
    for (int qi = 0; qi < 2; qi++) {
        f32x4 inv;
#pragma unroll
        for (int r = 0; r < 4; r++) inv[r] = 1.0f / sum_acc[qi][r];
#pragma unroll
        for (int nd = 0; nd < 4; nd++) {
            int d = nd * 16 + l15;
#pragma unroll
            for (int r = 0; r < 4; r++) {
                int s = s0 + wv * 32 + qi * 16 + quad * 4 + r;
                size_t row2 = (size_t)(b * 2048 + h * 128 + (s >> 4));
                int col2 = ((s & 15) << 6) + d;
                vals2[row2 * 1024 + col2] = f2bf(o_acc[qi][nd][r] * inv[r]);
            }
        }
    }
}

// ---------- launch ----------
extern "C" void kernel_launch(void* const* d_in, const int* in_sizes, int n_in,
                              void* d_out, int out_size, void* d_ws, size_t ws_size,
                              hipStream_t stream) {
    (void)in_sizes; (void)n_in; (void)out_size; (void)ws_size;
    const float* x      = (const float*)d_in[0];   // (4,2048,1024)
    const float* w_qkv  = (const float*)d_in[1];   // (3072,1024)
    const float* b_qkv  = (const float*)d_in[2];   // (3072,)
    const float* w_o    = (const float*)d_in[3];   // (1024,1024)
    const float* b_o    = (const float*)d_in[4];   // (1024,)
    float* out = (float*)d_out;

    char* ws = (char*)d_ws;
    u16* xb   = (u16*)(ws);                          // 16 MB  x bf16 (8192x1024)
    u16* wqb  = (u16*)(ws + 16777216);               // 6 MB   w_qkv bf16 (Q rows pre-scaled)
    u16* wob  = (u16*)(ws + 23068672);               // 2 MB   w_o bf16
    u16* qkvb = (u16*)(ws + 25165824);               // 48 MB  qkv bf16 (Q,K sections only)
    u16* vtb  = (u16*)(ws + 75497472);               // 16 MB  V^T bf16 (64bh x 64d x 2048s)
    u16* v2b  = (u16*)(ws + 92274688);               // 16 MB  vals2 bf16 (8192x1024)
    // scaled b_qkv lives in the v2b region: consumed by gemm_qkv, which
    // completes (same stream) before flash_attn overwrites v2b.
    float* bsc = (float*)(ws + 92274688);

    prep_inputs<<<6156, 256, 0, stream>>>(x, w_qkv, b_qkv, w_o, xb, wqb, wob, bsc);

    // qkv = x * w_qkv^T + b_qkv ; V section written transposed to vtb
    // (XCD remap, double-buffered staging)
    gemm_qkv<<<1536, 256, 0, stream>>>(xb, wqb, bsc, qkvb, vtb);

    // attention -> vals2 (bf16, quirky reshape layout); 512 blocks x 512 thr,
    // XCD-aware remap (8 bh x 8 s-tiles per XCD), 128-key tiles
    flash_attn<<<512, 512, 0, stream>>>(qkvb, vtb, v2b);

    // out = vals2 * w_o^T + b_o   (M=8192, N=1024, K=1024), fp32 out,
    // 128x64 tiles (R10-verified), XCD remap
    gemm_out<<<1024, 256, 0, stream>>>(v2b, wob, b_o, out);
}

// Round 13
// 236.285 us; speedup vs baseline: 1.0789x; 1.0789x over previous
//
#include <hip/hip_runtime.h>
#include <stdint.h>
#include <stddef.h>

#define DEVINL __device__ __forceinline__

typedef unsigned short u16;
typedef unsigned int u32;
typedef __attribute__((ext_vector_type(8))) short short8;
typedef __attribute__((ext_vector_type(4))) float f32x4;
typedef __attribute__((ext_vector_type(4))) u32 u32x4;
typedef __attribute__((ext_vector_type(2))) u32 u32x2;

// log2(e)/8 : folded into W_q / b_q so flash's exp2 needs no multiply
#define QSCALE 0.18033688011112042f

// ---------- helpers ----------
DEVINL u16 f2bf(float f) {
    u32 u = __builtin_bit_cast(u32, f);
    u32 r = (u + 0x7fffu + ((u >> 16) & 1u)) >> 16;   // RNE
    return (u16)r;
}

DEVINL void gld_lds16(const void* g, void* l) {
    __builtin_amdgcn_global_load_lds(
        (__attribute__((address_space(1))) u32*)(uintptr_t)g,
        (__attribute__((address_space(3))) u32*)l, 16, 0, 0);
}

// pack two fp32 -> bf16x2 by truncation (bias cancels: denominator sums the same bf16 P)
DEVINL u32 pack_bf16_trunc(float lo, float hi) {
    return __builtin_amdgcn_perm(__builtin_bit_cast(u32, hi),
                                 __builtin_bit_cast(u32, lo), 0x07060302u);
}

// cross-lane half swaps (gfx950): both outputs are used.
DEVINL void plswap32(u32 &a, u32 &b) {
#if __has_builtin(__builtin_amdgcn_permlane32_swap)
    u32x2 r = __builtin_amdgcn_permlane32_swap(a, b, false, false);
    a = r[0]; b = r[1];
#else
    asm("v_permlane32_swap_b32 %0, %1" : "+v"(a), "+v"(b));
#endif
}
DEVINL void plswap16(u32 &a, u32 &b) {
#if __has_builtin(__builtin_amdgcn_permlane16_swap)
    u32x2 r = __builtin_amdgcn_permlane16_swap(a, b, false, false);
    a = r[0]; b = r[1];
#else
    asm("v_permlane16_swap_b32 %0, %1" : "+v"(a), "+v"(b));
#endif
}

// ---------- fused input prep: casts + scale folding, one launch ----------
// blocks [0,4096): x -> xb ; [4096,5632): w_qkv -> wqb (Q rows scaled)
// [5632,6144): w_o -> wob ; [6144,6156): b_qkv scale -> bsc
__global__ void prep_inputs(const float* __restrict__ x, const float* __restrict__ wqkv,
                            const float* __restrict__ bqkv, const float* __restrict__ wo,
                            u16* __restrict__ xb, u16* __restrict__ wqb,
                            u16* __restrict__ wob, float* __restrict__ bsc) {
    int blk = blockIdx.x;
    if (blk < 6144) {
        const float* src; u16* dst; int base; bool qscale = false;
        if (blk < 4096)      { src = x;    dst = xb;  base = blk; }
        else if (blk < 5632) { src = wqkv; dst = wqb; base = blk - 4096; qscale = true; }
        else                 { src = wo;   dst = wob; base = blk - 5632; }
        int i = (base * 256 + threadIdx.x) * 8;
        float sc = 1.0f;
        if (qscale) { int row = i >> 10; if ((row % 192) < 64) sc = QSCALE; }
        float4 a = *(const float4*)(src + i);
        float4 c = *(const float4*)(src + i + 4);
        union { u16 s[8]; u32x4 v; } t;
        t.s[0] = f2bf(a.x * sc); t.s[1] = f2bf(a.y * sc); t.s[2] = f2bf(a.z * sc); t.s[3] = f2bf(a.w * sc);
        t.s[4] = f2bf(c.x * sc); t.s[5] = f2bf(c.y * sc); t.s[6] = f2bf(c.z * sc); t.s[7] = f2bf(c.w * sc);
        *(u32x4*)(dst + i) = t.v;
    } else {
        int i = (blk - 6144) * 256 + threadIdx.x;   // 0..3071
        float sc = ((i % 192) < 64) ? QSCALE : 1.0f;
        bsc[i] = bqkv[i] * sc;
    }
}

// ---------- QKV GEMM  qkv[M,3072] = x[M,K] * w_qkv[3072,K]^T + b ----------
// R13 = exact R9/R11 form (measured 76.8 us, the best): SINGLE-buffer 32 KB
// LDS, BK=64 flash-pattern zero-conflict geometry (linear dest + pre-swizzled
// source granule lgr=(lane&7)^(row&7); fragment reads XOR (l15&7)*8),
// XCD-aware 1-D remap.  (R12's 64 KB double-buffer regressed: occupancy
// 30->19.6%, FETCH 67->91 MB — m132 reproduced.  Reverted.)
// V-section columns (col%192 in [128,192)) are written TRANSPOSED straight to
// vt[bh][d][s]; Q/K go to qkvb.
__global__ void gemm_qkv(const u16* __restrict__ A, const u16* __restrict__ Bm,
                         const float* __restrict__ bias, u16* __restrict__ qkvb,
                         u16* __restrict__ vtb) {
    const int K = 1024, N = 3072;
    __shared__ u16 As[128 * 64];   // 16 KB: 128 rows x 64 k (swizzled granules)
    __shared__ u16 Bs[128 * 64];   // 16 KB
    const int tid = threadIdx.x;
    const int lane = tid & 63;
    const int wv = tid >> 6, wr = wv >> 1, wc = wv & 1;
    const int l15 = lane & 15, quad = lane >> 4;
    const int e7 = (l15 & 7) * 8;              // u16-unit XOR for swizzled reads
    const int id = blockIdx.x;                 // 0..1535
    const int xcd = id & 7, rr = id >> 3;      // rr: 0..191
    const int m0 = ((xcd << 3) + rr / 24) * 128;
    const int n0 = (rr % 24) * 128;

    f32x4 acc[4][4];
#pragma unroll
    for (int i = 0; i < 4; i++)
#pragma unroll
        for (int j = 0; j < 4; j++) acc[i][j] = (f32x4){0.f, 0.f, 0.f, 0.f};

    const u16* Ab = A + (size_t)m0 * K;
    const u16* Bb = Bm + (size_t)n0 * K;
    const int lrow = lane >> 3;
    const int lgr  = (lane & 7) ^ lrow;
    const int r0   = wv * 8 + lrow;

    for (int k0 = 0; k0 < K; k0 += 64) {
#pragma unroll
        for (int j = 0; j < 4; j++) {
            int row = j * 32 + r0;
            gld_lds16(Ab + (size_t)row * K + k0 + lgr * 8, (char*)As + (size_t)(j * 256 + tid) * 16);
            gld_lds16(Bb + (size_t)row * K + k0 + lgr * 8, (char*)Bs + (size_t)(j * 256 + tid) * 16);
        }
        __syncthreads();
#pragma unroll
        for (int ks = 0; ks < 2; ks++) {
            short8 af[4], bf8[4];
#pragma unroll
            for (int mi = 0; mi < 4; mi++)
                af[mi] = *(const short8*)(As + (wr * 64 + mi * 16 + l15) * 64 + ((ks * 32 + quad * 8) ^ e7));
#pragma unroll
            for (int ni = 0; ni < 4; ni++)
                bf8[ni] = *(const short8*)(Bs + (wc * 64 + ni * 16 + l15) * 64 + ((ks * 32 + quad * 8) ^ e7));
#pragma unroll
            for (int mi = 0; mi < 4; mi++)
#pragma unroll
                for (int ni = 0; ni < 4; ni++)
                    acc[mi][ni] = __builtin_amdgcn_mfma_f32_16x16x32_bf16(af[mi], bf8[ni], acc[mi][ni], 0, 0, 0);
        }
        __syncthreads();
    }

#pragma unroll
    for (int mi = 0; mi < 4; mi++) {
        int row_b = m0 + wr * 64 + mi * 16 + quad * 4;
#pragma unroll
        for (int ni = 0; ni < 4; ni++) {
            int c0 = n0 + wc * 64 + ni * 16;          // group base (16-aligned)
            int sec0 = c0 % 192;                       // section offset, wave-uniform
            float bv = bias[c0 + l15];
            float v0 = acc[mi][ni][0] + bv;
            float v1 = acc[mi][ni][1] + bv;
            float v2 = acc[mi][ni][2] + bv;
            float v3 = acc[mi][ni][3] + bv;
            if (sec0 >= 128) {
                // V element: transpose-store to vt[bh][d][s], 4 consecutive s
                int hh = c0 / 192;
                int b = row_b >> 11;
                int s = row_b & 2047;
                int d = sec0 - 128 + l15;
                u32 lo = (u32)f2bf(v0) | ((u32)f2bf(v1) << 16);
                u32 hi = (u32)f2bf(v2) | ((u32)f2bf(v3) << 16);
                *(u32x2*)(vtb + ((size_t)((b * 16 + hh) * 64 + d)) * 2048 + s) = (u32x2){lo, hi};
            } else {
                int col = c0 + l15;
                qkvb[(size_t)(row_b + 0) * N + col] = f2bf(v0);
                qkvb[(size_t)(row_b + 1) * N + col] = f2bf(v1);
                qkvb[(size_t)(row_b + 2) * N + col] = f2bf(v2);
                qkvb[(size_t)(row_b + 3) * N + col] = f2bf(v3);
            }
        }
    }
}

// ---------- out GEMM  out[M,1024] = vals2[M,K] * w_o[1024,K]^T + b_o ----------
// R13 = R10/R12-verified 128x64 / 1024-block form (4 blocks/CU).
// BK=64 flash-pattern LDS (zero-conflict), XCD remap.
__global__ void gemm_out(const u16* __restrict__ A, const u16* __restrict__ Bm,
                         const float* __restrict__ bias, float* __restrict__ C) {
    const int K = 1024, N = 1024;
    __shared__ u16 As[128 * 64];   // 16 KB
    __shared__ u16 Bs[64 * 64];    // 8 KB
    const int tid = threadIdx.x;
    const int lane = tid & 63;
    const int wv = tid >> 6, wr = wv >> 1, wc = wv & 1;
    const int l15 = lane & 15, quad = lane >> 4;
    const int e7 = (l15 & 7) * 8;
    const int id = blockIdx.x;                 // 0..1023
    const int xcd = id & 7, rr = id >> 3;      // rr: 0..127
    const int m0 = ((xcd << 3) + (rr >> 4)) * 128;
    const int n0 = (rr & 15) * 64;

    f32x4 acc[4][2];
#pragma unroll
    for (int i = 0; i < 4; i++)
#pragma unroll
        for (int j = 0; j < 2; j++) acc[i][j] = (f32x4){0.f, 0.f, 0.f, 0.f};

    const u16* Ab = A + (size_t)m0 * K;
    const u16* Bb = Bm + (size_t)n0 * K;
    const int lrow = lane >> 3;
    const int lgr  = (lane & 7) ^ lrow;
    const int r0   = wv * 8 + lrow;

    for (int k0 = 0; k0 < K; k0 += 64) {
#pragma unroll
        for (int j = 0; j < 4; j++)
            gld_lds16(Ab + (size_t)(j * 32 + r0) * K + k0 + lgr * 8,
                      (char*)As + (size_t)(j * 256 + tid) * 16);
#pragma unroll
        for (int j = 0; j < 2; j++)
            gld_lds16(Bb + (size_t)(j * 32 + r0) * K + k0 + lgr * 8,
                      (char*)Bs + (size_t)(j * 256 + tid) * 16);
        __syncthreads();
#pragma unroll
        for (int ks = 0; ks < 2; ks++) {
            short8 af[4], bf8[2];
#pragma unroll
            for (int mi = 0; mi < 4; mi++)
                af[mi] = *(const short8*)(As + (wr * 64 + mi * 16 + l15) * 64 + ((ks * 32 + quad * 8) ^ e7));
#pragma unroll
            for (int ni = 0; ni < 2; ni++)
                bf8[ni] = *(const short8*)(Bs + (wc * 32 + ni * 16 + l15) * 64 + ((ks * 32 + quad * 8) ^ e7));
#pragma unroll
            for (int mi = 0; mi < 4; mi++)
#pragma unroll
                for (int ni = 0; ni < 2; ni++)
                    acc[mi][ni] = __builtin_amdgcn_mfma_f32_16x16x32_bf16(af[mi], bf8[ni], acc[mi][ni], 0, 0, 0);
        }
        __syncthreads();
    }

#pragma unroll
    for (int mi = 0; mi < 4; mi++) {
        int row_b = m0 + wr * 64 + mi * 16 + quad * 4;
#pragma unroll
        for (int ni = 0; ni < 2; ni++) {
            int col = n0 + wc * 32 + ni * 16 + l15;
            float bv = bias[col];
#pragma unroll
            for (int r = 0; r < 4; r++)
                C[(size_t)(row_b + r) * N + col] = acc[mi][ni][r] + bv;
        }
    }
}

// ---------- flash attention (R13 = R11/R12 form, measured <=76 us) ----------
// 16x16 MFMA, in-register P via permlane swaps, ZERO-C init, 8-wave 256-q
// blocks, 128-key tiles staged as two verified 64x64 sub-tiles, double-buffer,
// one barrier per 128 keys, XCD-aware remap, setprio.
__launch_bounds__(512, 4)
__global__ void flash_attn(const u16* __restrict__ qkv, const u16* __restrict__ vt,
                           u16* __restrict__ vals2) {
    __shared__ u16 Ks[2][2][64 * 64];   // [dbuf][subtile]: 64 keys x 64 d (swizzled)
    __shared__ u16 Vts[2][2][64 * 64];  // [dbuf][subtile]: 64 d x 64 keys (swizzled)

    const int tid = threadIdx.x;
    const int lane = tid & 63, wv = tid >> 6;      // wv: 0..7
    const int l15 = lane & 15, quad = lane >> 4;
    const int e7 = (l15 & 7) * 8;          // u16-unit XOR for swizzled reads
    // XCD-aware decode of the 1-D block id (512 blocks: 8 bh x 8 s-tiles per XCD)
    const int id = blockIdx.x;
    const int m = id >> 3;                  // 0..63
    const int bh = ((id & 7) << 3) + (m >> 3);
    const int s0 = (m & 7) << 8;            // 256-q tiles
    const int b = bh >> 4, h = bh & 15;

    // Q fragments in registers (q rows pre-scaled by log2e/8 at cast time)
    short8 qf[2][2];
    const u16* qbase = qkv + (size_t)(b * 2048 + s0 + wv * 32) * 3072 + h * 192;
#pragma unroll
    for (int qi = 0; qi < 2; qi++)
#pragma unroll
        for (int ks = 0; ks < 2; ks++)
            qf[qi][ks] = *(const short8*)(qbase + (size_t)(qi * 16 + l15) * 3072 + ks * 32 + quad * 8);

    f32x4 o_acc[2][4];
    f32x4 sum_acc[2];
#pragma unroll
    for (int qi = 0; qi < 2; qi++) {
        sum_acc[qi] = (f32x4){0.f, 0.f, 0.f, 0.f};
#pragma unroll
        for (int nd = 0; nd < 4; nd++) o_acc[qi][nd] = (f32x4){0.f, 0.f, 0.f, 0.f};
    }
    const f32x4 fzero = (f32x4){0.f, 0.f, 0.f, 0.f};

    const u16* kg = qkv + (size_t)(b * 2048) * 3072 + h * 192 + 64;
    const u16* vg = vt + (size_t)bh * 64 * 2048;

    // staging geometry: thread covers row wv*8 + (lane>>3) (8 waves -> 64 rows);
    // physical granule lane&7 holds logical granule (lane&7)^(row&7).
    const int lrow = lane >> 3;
    const int lgr  = (lane & 7) ^ lrow;
    const int r0   = wv * 8 + lrow;

    const short8 ones = (short8){0x3F80, 0x3F80, 0x3F80, 0x3F80, 0x3F80, 0x3F80, 0x3F80, 0x3F80};

    // prologue: stage tile 0 (both sub-tiles) into buffer 0
#pragma unroll
    for (int st = 0; st < 2; st++) {
        gld_lds16(kg + (size_t)(st * 64 + r0) * 3072 + lgr * 8,
                  (char*)&Ks[0][st][0] + (size_t)tid * 16);
        gld_lds16(vg + (size_t)r0 * 2048 + st * 64 + lgr * 8,
                  (char*)&Vts[0][st][0] + (size_t)tid * 16);
    }
    __syncthreads();

    int cur = 0;
    for (int kb = 0; kb < 2048; kb += 128) {
        // prefetch next 128-key tile into the other buffer (hidden under compute)
        if (kb + 128 < 2048) {
            int nb = cur ^ 1;
#pragma unroll
            for (int st = 0; st < 2; st++) {
                gld_lds16(kg + (size_t)(kb + 128 + st * 64 + r0) * 3072 + lgr * 8,
                          (char*)&Ks[nb][st][0] + (size_t)tid * 16);
                gld_lds16(vg + (size_t)r0 * 2048 + kb + 128 + st * 64 + lgr * 8,
                          (char*)&Vts[nb][st][0] + (size_t)tid * 16);
            }
        }

#pragma unroll
        for (int st = 0; st < 2; st++) {
            const u16* Kc = &Ks[cur][st][0];
            const u16* Vc = &Vts[cur][st][0];

            // S^T = K * Q^T : s_acc[ki][qi] -> key = ki*16+quad*4+r, q = qi*16+l15
            // first k-slice uses C=fzero (no per-tile accumulator zero-init movs)
            f32x4 s_acc[4][2];
            __builtin_amdgcn_s_setprio(1);
#pragma unroll
            for (int ki = 0; ki < 4; ki++) {
                short8 kf0 = *(const short8*)(Kc + (ki * 16 + l15) * 64 + ((quad * 8) ^ e7));
                short8 kf1 = *(const short8*)(Kc + (ki * 16 + l15) * 64 + ((32 + quad * 8) ^ e7));
#pragma unroll
                for (int qi = 0; qi < 2; qi++)
                    s_acc[ki][qi] = __builtin_amdgcn_mfma_f32_16x16x32_bf16(kf0, qf[qi][0], fzero, 0, 0, 0);
#pragma unroll
                for (int qi = 0; qi < 2; qi++)
                    s_acc[ki][qi] = __builtin_amdgcn_mfma_f32_16x16x32_bf16(kf1, qf[qi][1], s_acc[ki][qi], 0, 0, 0);
            }
            __builtin_amdgcn_s_setprio(0);

            // P = exp2(S^T) -> pack bf16 pairs -> permlane swaps build PV A-frags
            short8 ap[2][2];   // [qi][c]: P[q=l15][key=c*32+quad*8+0..7]
#pragma unroll
            for (int c = 0; c < 2; c++)
#pragma unroll
                for (int qi = 0; qi < 2; qi++) {
                    u32 w0 = pack_bf16_trunc(__builtin_amdgcn_exp2f(s_acc[2 * c][qi][0]),
                                             __builtin_amdgcn_exp2f(s_acc[2 * c][qi][1]));
                    u32 w1 = pack_bf16_trunc(__builtin_amdgcn_exp2f(s_acc[2 * c][qi][2]),
                                             __builtin_amdgcn_exp2f(s_acc[2 * c][qi][3]));
                    u32 w2 = pack_bf16_trunc(__builtin_amdgcn_exp2f(s_acc[2 * c + 1][qi][0]),
                                             __builtin_amdgcn_exp2f(s_acc[2 * c + 1][qi][1]));
                    u32 w3 = pack_bf16_trunc(__builtin_amdgcn_exp2f(s_acc[2 * c + 1][qi][2]),
                                             __builtin_amdgcn_exp2f(s_acc[2 * c + 1][qi][3]));
                    plswap32(w0, w2);
                    plswap32(w1, w3);
                    plswap16(w0, w2);
                    plswap16(w1, w3);
                    u32x4 wf = (u32x4){w0, w1, w2, w3};
                    ap[qi][c] = __builtin_bit_cast(short8, wf);
                }

            // PV over 2 chunks of 32 keys; denominator via ones-column MFMA
#pragma unroll
            for (int c = 0; c < 2; c++) {
#pragma unroll
                for (int qi = 0; qi < 2; qi++)
                    sum_acc[qi] = __builtin_amdgcn_mfma_f32_16x16x32_bf16(ap[qi][c], ones, sum_acc[qi], 0, 0, 0);
                __builtin_amdgcn_s_setprio(1);
#pragma unroll
                for (int nd = 0; nd < 4; nd++) {
                    short8 bv = *(const short8*)(Vc + (nd * 16 + l15) * 64 + ((c * 32 + quad * 8) ^ e7));
#pragma unroll
                    for (int qi = 0; qi < 2; qi++)
                        o_acc[qi][nd] = __builtin_amdgcn_mfma_f32_16x16x32_bf16(ap[qi][c], bv, o_acc[qi][nd], 0, 0, 0);
                }
                __builtin_amdgcn_s_setprio(0);
            }
        }

        __syncthreads();   // implicit vmcnt(0): prefetch complete; all reads of [cur] done
        cur ^= 1;
    }

    // epilogue: normalize (sum is broadcast across l15 by the ones-MFMA) and
    // write vals2 in the no-head-transpose reshape layout.
#pragma unroll
    for (int qi = 0; qi < 2; qi++) {
        f32x4 inv;
#pragma unroll
        for (int r = 0; r < 4; r++) inv[r] = 1.0f / sum_acc[qi][r];
#pragma unroll
        for (int nd = 0; nd < 4; nd++) {
            int d = nd * 16 + l15;
#pragma unroll
            for (int r = 0; r < 4; r++) {
                int s = s0 + wv * 32 + qi * 16 + quad * 4 + r;
                size_t row2 = (size_t)(b * 2048 + h * 128 + (s >> 4));
                int col2 = ((s & 15) << 6) + d;
                vals2[row2 * 1024 + col2] = f2bf(o_acc[qi][nd][r] * inv[r]);
            }
        }
    }
}

// ---------- launch ----------
extern "C" void kernel_launch(void* const* d_in, const int* in_sizes, int n_in,
                              void* d_out, int out_size, void* d_ws, size_t ws_size,
                              hipStream_t stream) {
    (void)in_sizes; (void)n_in; (void)out_size; (void)ws_size;
    const float* x      = (const float*)d_in[0];   // (4,2048,1024)
    const float* w_qkv  = (const float*)d_in[1];   // (3072,1024)
    const float* b_qkv  = (const float*)d_in[2];   // (3072,)
    const float* w_o    = (const float*)d_in[3];   // (1024,1024)
    const float* b_o    = (const float*)d_in[4];   // (1024,)
    float* out = (float*)d_out;

    char* ws = (char*)d_ws;
    u16* xb   = (u16*)(ws);                          // 16 MB  x bf16 (8192x1024)
    u16* wqb  = (u16*)(ws + 16777216);               // 6 MB   w_qkv bf16 (Q rows pre-scaled)
    u16* wob  = (u16*)(ws + 23068672);               // 2 MB   w_o bf16
    u16* qkvb = (u16*)(ws + 25165824);               // 48 MB  qkv bf16 (Q,K sections only)
    u16* vtb  = (u16*)(ws + 75497472);               // 16 MB  V^T bf16 (64bh x 64d x 2048s)
    u16* v2b  = (u16*)(ws + 92274688);               // 16 MB  vals2 bf16 (8192x1024)
    // scaled b_qkv lives in the v2b region: consumed by gemm_qkv, which
    // completes (same stream) before flash_attn overwrites v2b.
    float* bsc = (float*)(ws + 92274688);

    prep_inputs<<<6156, 256, 0, stream>>>(x, w_qkv, b_qkv, w_o, xb, wqb, wob, bsc);

    // qkv = x * w_qkv^T + b_qkv ; V section written transposed to vtb (XCD remap)
    gemm_qkv<<<1536, 256, 0, stream>>>(xb, wqb, bsc, qkvb, vtb);

    // attention -> vals2 (bf16, quirky reshape layout); 512 blocks x 512 thr,
    // XCD-aware remap (8 bh x 8 s-tiles per XCD), 128-key tiles
    flash_attn<<<512, 512, 0, stream>>>(qkvb, vtb, v2b);

    // out = vals2 * w_o^T + b_o   (M=8192, N=1024, K=1024), fp32 out,
    // 128x64 tiles (R10-verified), XCD remap
    gemm_out<<<1024, 256, 0, stream>>>(v2b, wob, b_o, out);
}